// Round 7
// baseline (71772.833 us; speedup 1.0000x reference)
//
#include <hip/hip_runtime.h>

// Persistent-LSTM MI355X — Round 13: push-model mailbox exchange.
// R12's early-hint regression isolated the mechanism: consumers' data reads
// launched before sibling stores landed -> ~2 retry rounds (~2L) per step.
// R13 removes the pull-model's serial hops entirely: producers PUSH their
// 8 h-values into each consumer block's private mailbox as self-validating
// u64 {tag|float} words (R12's proven format). Consumer waves free-run-poll
// their OWN 2KB slice; when tags pass, data is already in registers.
//   chain: bar2 -> broadcast issue -> flight L -> detect (<=1 round)
//   vs R11: all-8 drain L -> tag store -> flight L -> detect L/4 -> read L.
// Measured failure boundaries respected:
//   - polled lines are 1-writer/1-reader (R7's storm: 256 waves/shared line)
//   - BOTH barriers stay (every decoupled variant cost +2us/step: R7/R8/R10)
//   - geometry unchanged 256x512 (R9's VGPR cap)
//   - no premature hint (R12)
// WAR/freshness: word tag t+2 in parity p requires its producer to have
// completed step t+1, which requires observing ALL its words >= t+1, which
// requires every block's step-t staging reads complete (stage precedes
// publish in program order). 0xAA poison tag is negative signed -> stale.
// Mailbox = u64 mbox[2][256][256][8] = 8MB. ws_size is unverified ->
// launcher falls back to the R11 champion kernel (verbatim) if ws < 8MB.

#define H      2048
#define TSTEPS 8192
#define FEAT   128
#define NBLK   256
#define NTHR   512

typedef float vf4 __attribute__((ext_vector_type(4)));
typedef float vf2 __attribute__((ext_vector_type(2)));
typedef unsigned long long u64;
typedef unsigned int u32;

__device__ __forceinline__ float sigm(float xv) {
  return __builtin_amdgcn_rcpf(1.0f + __expf(-xv));
}
__device__ __forceinline__ float tanh_(float xv) {
  return 1.0f - 2.0f * __builtin_amdgcn_rcpf(__expf(2.0f * xv) + 1.0f);
}

__device__ __forceinline__ u64 aload64(const u64* p) {
  return __hip_atomic_load(p, __ATOMIC_RELAXED, __HIP_MEMORY_SCOPE_AGENT);
}
__device__ __forceinline__ u32 aload32(const u32* p) {
  return __hip_atomic_load(p, __ATOMIC_RELAXED, __HIP_MEMORY_SCOPE_AGENT);
}
__device__ __forceinline__ void astoref(float* p, float v) {
  __hip_atomic_store(p, v, __ATOMIC_RELAXED, __HIP_MEMORY_SCOPE_AGENT);
}
__device__ __forceinline__ void astoreu(u32* p, u32 v) {
  __hip_atomic_store(p, v, __ATOMIC_RELAXED, __HIP_MEMORY_SCOPE_AGENT);
}
__device__ __forceinline__ void astore64(u64* p, u64 v) {
  __hip_atomic_store(p, v, __ATOMIC_RELAXED, __HIP_MEMORY_SCOPE_AGENT);
}
__device__ __forceinline__ int  tag_of(u64 d) { return (int)(u32)(d >> 32); }
__device__ __forceinline__ float val_of(u64 d) { return __uint_as_float((u32)d); }
__device__ __forceinline__ u64  pack(int tag, float v) {
  return ((u64)(u32)tag << 32) | (u64)__float_as_uint(v);
}

#define DECLG(g) vf4 w##g##_0, w##g##_1, w##g##_2, w##g##_3, \
                     w##g##_4, w##g##_5, w##g##_6, w##g##_7; \
                 vf2 wih##g; float bias##g; float acc##g;

#define LOADG(g) { \
  const int row_ = (g) * H + j; \
  const float* wr_ = W_hh + (long)row_ * H; \
  w##g##_0 = *(const vf4*)(wr_ + 4*(ln      )); \
  w##g##_1 = *(const vf4*)(wr_ + 4*(ln +  64)); \
  w##g##_2 = *(const vf4*)(wr_ + 4*(ln + 128)); \
  w##g##_3 = *(const vf4*)(wr_ + 4*(ln + 192)); \
  w##g##_4 = *(const vf4*)(wr_ + 4*(ln + 256)); \
  w##g##_5 = *(const vf4*)(wr_ + 4*(ln + 320)); \
  w##g##_6 = *(const vf4*)(wr_ + 4*(ln + 384)); \
  w##g##_7 = *(const vf4*)(wr_ + 4*(ln + 448)); \
  wih##g  = *(const vf2*)(W_ih + (long)row_ * FEAT + 2*ln); \
  bias##g = b_ih[row_] + b_hh[row_]; }

// Opaque pin: weights become non-rematerializable (cannot re-sink into loop).
#define PIN(g) asm volatile("" : \
  "+v"(w##g##_0), "+v"(w##g##_1), "+v"(w##g##_2), "+v"(w##g##_3), \
  "+v"(w##g##_4), "+v"(w##g##_5), "+v"(w##g##_6), "+v"(w##g##_7), \
  "+v"(wih##g), "+v"(bias##g));

#define LDSREAD(k, ldsrow) \
  const vf4 hv##k = *(const vf4*)&(ldsrow)[4*(ln + 64*(k))];

#define FMA_G(g, c) \
  acc##g = __builtin_fmaf(w##g##_##c.x, h4_.x, acc##g); \
  acc##g = __builtin_fmaf(w##g##_##c.y, h4_.y, acc##g); \
  acc##g = __builtin_fmaf(w##g##_##c.z, h4_.z, acc##g); \
  acc##g = __builtin_fmaf(w##g##_##c.w, h4_.w, acc##g);

#define FMA_C(c) { const vf4 h4_ = hv##c; \
  FMA_G(0, c) FMA_G(1, c) FMA_G(2, c) FMA_G(3, c) }

#define REDUCE(g) { float a_ = acc##g; \
  a_ += __shfl_xor(a_, 1);  a_ += __shfl_xor(a_, 2);  a_ += __shfl_xor(a_, 4); \
  a_ += __shfl_xor(a_, 8);  a_ += __shfl_xor(a_, 16); a_ += __shfl_xor(a_, 32); \
  acc##g = a_ + bias##g; }

// ============================ MAILBOX KERNEL ============================

// Wave wv polls its block's OWN mailbox row (32 producer entries x 64B =
// 2KB, contiguous, 1-writer/1-reader per entry). Lane ln owns entry
// e=ln>>1, half hf=ln&1 -> 4 u64 words (units 8p+4hf..+3). Free-running
// dependent rounds; stale lanes reload. Exit => floats in registers.
// Deposit h-index: 8*(wv*32+e)+4*hf+k = wv*256 + 4*ln + k (contiguous).
__device__ __forceinline__ void mbox_poll_stage(const u64* __restrict__ mrow,
                                                int tgt,
                                                float* __restrict__ ldsrow,
                                                int wv, int ln) {
  const u64* hp = mrow + (((wv << 5) + (ln >> 1)) << 3) + ((ln & 1) << 2);
  u64 d0 = aload64(hp + 0);
  u64 d1 = aload64(hp + 1);
  u64 d2 = aload64(hp + 2);
  u64 d3 = aload64(hp + 3);
  while (!__all((tag_of(d0) >= tgt) & (tag_of(d1) >= tgt) &
                (tag_of(d2) >= tgt) & (tag_of(d3) >= tgt))) {
    __builtin_amdgcn_s_sleep(1);
    if (tag_of(d0) < tgt) d0 = aload64(hp + 0);
    if (tag_of(d1) < tgt) d1 = aload64(hp + 1);
    if (tag_of(d2) < tgt) d2 = aload64(hp + 2);
    if (tag_of(d3) < tgt) d3 = aload64(hp + 3);
  }
  vf4 hv;
  hv.x = val_of(d0);
  hv.y = val_of(d1);
  hv.z = val_of(d2);
  hv.w = val_of(d3);
  *(vf4*)&ldsrow[wv * 256 + 4 * ln] = hv;
}

__global__ __launch_bounds__(NTHR, 2)
void lstm_mbox(const float* __restrict__ x,
               const float* __restrict__ W_ih,
               const float* __restrict__ W_hh,
               const float* __restrict__ b_ih,
               const float* __restrict__ b_hh,
               const float* __restrict__ W_lin,
               const float* __restrict__ b_lin,
               const float* __restrict__ W_out,
               const float* __restrict__ b_out,
               float* __restrict__ out,
               float* __restrict__ ws)
{
  const int tid = threadIdx.x;
  const int b   = blockIdx.x;
  const int wv  = tid >> 6;
  const int ln  = tid & 63;

  // mbox[par][c][p][w]: u64 word = {tag | h[8p+w] bits}; 2x256x256x8 = 8MB.
  u64* mbox = (u64*)ws;

  __shared__ __align__(16) float h_lds[2][H];
  __shared__ __align__(16) float hshare[8];   // block's 8 hvals for broadcast

  // h_0 = 0: zero parity-0 LDS row (512 threads x 16B)
  *(vf4*)&h_lds[0][4 * tid] = (vf4)(0.0f);

  // ---- persistent weights: load then pin ----
  const int j = b * 8 + wv;
  DECLG(0) DECLG(1) DECLG(2) DECLG(3)
  LOADG(0) LOADG(1) LOADG(2) LOADG(3)
  PIN(0) PIN(1) PIN(2) PIN(3)

  __syncthreads();

  // broadcast target: thread tid serves consumer cc = tid>>1, half hf.
  const int cc = tid >> 1;
  const int hf = tid & 1;

  float cst = 0.0f;

  #pragma unroll 1
  for (int t = 0; t < TSTEPS; ++t) {
    const vf2 xr = *(const vf2*)(x + (long)t * FEAT + 2 * ln);
    float* ldsrow = h_lds[t & 1];

    if (t > 0)
      mbox_poll_stage(mbox + (((long)(t & 1) * NBLK + b) * NBLK << 3),
                      t, ldsrow, wv, ln);
    __syncthreads();   // barrier #1: all slices staged before any LDS read

    LDSREAD(0, ldsrow) LDSREAD(1, ldsrow) LDSREAD(2, ldsrow) LDSREAD(3, ldsrow)
    LDSREAD(4, ldsrow) LDSREAD(5, ldsrow) LDSREAD(6, ldsrow) LDSREAD(7, ldsrow)

    acc0 = wih0.x * xr.x + wih0.y * xr.y;
    acc1 = wih1.x * xr.x + wih1.y * xr.y;
    acc2 = wih2.x * xr.x + wih2.y * xr.y;
    acc3 = wih3.x * xr.x + wih3.y * xr.y;

    FMA_C(0) FMA_C(1) FMA_C(2) FMA_C(3)
    FMA_C(4) FMA_C(5) FMA_C(6) FMA_C(7)

    REDUCE(0) REDUCE(1) REDUCE(2) REDUCE(3)

    // gate order [i, f, g, o]
    const float iv = sigm(acc0);
    const float fv = sigm(acc1);
    const float gv = tanh_(acc2);
    const float ov = sigm(acc3);
    cst = fv * cst + iv * gv;
    const float hval = ov * tanh_(cst);

    // publish h_{t+1}: gather block's 8 hvals in LDS (barrier #2 orders),
    // then PUSH: each thread writes 4 self-validating words (32B) into
    // consumer cc's mailbox entry for this block. No drain, no tag hop —
    // consumers validate per-word. Stores fly while we loop to poll.
    if (ln == 0) hshare[wv] = hval;
    __syncthreads();   // barrier #2
    {
      u64* ep = mbox + ((((long)((t + 1) & 1) * NBLK + cc) * NBLK + b) << 3)
                     + (hf << 2);
      const int tg = t + 1;
      astore64(ep + 0, pack(tg, hshare[hf * 4 + 0]));
      astore64(ep + 1, pack(tg, hshare[hf * 4 + 1]));
      astore64(ep + 2, pack(tg, hshare[hf * 4 + 2]));
      astore64(ep + 3, pack(tg, hshare[hf * 4 + 3]));
    }
  }

  // ---- head phase 1: ylin[j] = b_lin[j] + dot(W_lin[j,:], h_final) ----
  // h_final tags = TSTEPS (even -> parity 0).
  {
    float* ldsrow = h_lds[0];
    mbox_poll_stage(mbox + ((long)b * NBLK << 3), TSTEPS, ldsrow, wv, ln);
    __syncthreads();

    float a0 = 0.0f;
    const float* wl = W_lin + (long)j * H;
    #pragma unroll
    for (int k = 0; k < 8; ++k) {
      const vf4 h4 = *(const vf4*)&ldsrow[4 * (ln + 64 * k)];
      const vf4 u  = *(const vf4*)(wl + 4 * (ln + 64 * k));
      a0 += u.x * h4.x + u.y * h4.y + u.z * h4.z + u.w * h4.w;
    }
    a0 += __shfl_xor(a0, 1);  a0 += __shfl_xor(a0, 2);  a0 += __shfl_xor(a0, 4);
    a0 += __shfl_xor(a0, 8);  a0 += __shfl_xor(a0, 16); a0 += __shfl_xor(a0, 32);

    // ylin -> block 0's parity-1 mailbox row, tag TSTEPS+1 (odd, monotonic).
    // Safe: we observed tag TSTEPS from ALL producers => every block
    // finished its parity-1 (step 8191) staging reads.
    if (ln == 0) hshare[wv] = a0 + b_lin[j];
    __syncthreads();
    if (tid < 2) {
      u64* ep = mbox + ((((long)NBLK + 0) * NBLK + b) << 3) + (tid << 2);
      astore64(ep + 0, pack(TSTEPS + 1, hshare[tid * 4 + 0]));
      astore64(ep + 1, pack(TSTEPS + 1, hshare[tid * 4 + 1]));
      astore64(ep + 2, pack(TSTEPS + 1, hshare[tid * 4 + 2]));
      astore64(ep + 3, pack(TSTEPS + 1, hshare[tid * 4 + 3]));
    }
  }

  // ---- head phase 2: y = ylin @ W_out.T + b_out (block 0) ----
  if (b == 0) {
    // all 8 waves poll+stage ylin (256 producer entries in OUR parity-1 row)
    mbox_poll_stage(mbox + ((long)NBLK * NBLK << 3), TSTEPS + 1,
                    h_lds[1], wv, ln);
    __syncthreads();
    if (wv == 0) {
      float p0 = 0.0f, p1 = 0.0f;
      #pragma unroll
      for (int k = 0; k < 32; ++k) {
        const float y = h_lds[1][ln + 64 * k];
        p0 = __builtin_fmaf(W_out[ln + 64 * k],     y, p0);
        p1 = __builtin_fmaf(W_out[H + ln + 64 * k], y, p1);
      }
      p0 += __shfl_xor(p0, 1);  p0 += __shfl_xor(p0, 2);  p0 += __shfl_xor(p0, 4);
      p0 += __shfl_xor(p0, 8);  p0 += __shfl_xor(p0, 16); p0 += __shfl_xor(p0, 32);
      p1 += __shfl_xor(p1, 1);  p1 += __shfl_xor(p1, 2);  p1 += __shfl_xor(p1, 4);
      p1 += __shfl_xor(p1, 8);  p1 += __shfl_xor(p1, 16); p1 += __shfl_xor(p1, 32);
      if (ln == 0) {
        out[0] = p0 + b_out[0];
        out[1] = p1 + b_out[1];
      }
    }
  }
  // drain any in-flight broadcast stores before wave exit
  asm volatile("s_waitcnt vmcnt(0)" ::: "memory");
}

// ===================== R11 CHAMPION KERNEL (fallback) =====================

__device__ __forceinline__ void poll_and_stage(const u32* __restrict__ slots,
                                               const float* __restrict__ hsrc,
                                               int tgt,
                                               float* __restrict__ ldsrow,
                                               int wv, int ln) {
  const u32* sp = slots + wv * 32 + (ln & 31);
  const bool act = (ln < 32);
  int v0 = act ? (int)aload32(sp) : 0x7fffffff;
  int v1 = act ? (int)aload32(sp) : 0x7fffffff;
  while (!__all(v0 >= tgt)) {
    __builtin_amdgcn_s_sleep(1);
    v0 = v1;
    v1 = act ? (int)aload32(sp) : 0x7fffffff;
  }
  const int base = wv * 256 + 4 * ln;
  const u64* hp = (const u64*)(hsrc + base);
  const u64 d0 = aload64(hp);
  const u64 d1 = aload64(hp + 1);
  vf4 hv;
  hv.x = __uint_as_float((u32)d0);
  hv.y = __uint_as_float((u32)(d0 >> 32));
  hv.z = __uint_as_float((u32)d1);
  hv.w = __uint_as_float((u32)(d1 >> 32));
  *(vf4*)&ldsrow[base] = hv;
}

__global__ __launch_bounds__(NTHR, 2)
void lstm_persist(const float* __restrict__ x,
                  const float* __restrict__ W_ih,
                  const float* __restrict__ W_hh,
                  const float* __restrict__ b_ih,
                  const float* __restrict__ b_hh,
                  const float* __restrict__ W_lin,
                  const float* __restrict__ b_lin,
                  const float* __restrict__ W_out,
                  const float* __restrict__ b_out,
                  float* __restrict__ out,
                  float* __restrict__ ws)
{
  const int tid = threadIdx.x;
  const int b   = blockIdx.x;
  const int wv  = tid >> 6;
  const int ln  = tid & 63;

  float* hbuf0 = ws;
  float* hbuf1 = ws + H;
  u32*   slots = (u32*)(ws + 2 * H);

  __shared__ __align__(16) float h_lds[2][H];

  *(vf4*)&h_lds[0][4 * tid] = (vf4)(0.0f);

  const int j = b * 8 + wv;
  DECLG(0) DECLG(1) DECLG(2) DECLG(3)
  LOADG(0) LOADG(1) LOADG(2) LOADG(3)
  PIN(0) PIN(1) PIN(2) PIN(3)

  __syncthreads();

  float cst = 0.0f;

  #pragma unroll 1
  for (int t = 0; t < TSTEPS; ++t) {
    const vf2 xr = *(const vf2*)(x + (long)t * FEAT + 2 * ln);
    float* ldsrow = h_lds[t & 1];

    if (t > 0)
      poll_and_stage(slots, (t & 1) ? hbuf1 : hbuf0, t, ldsrow, wv, ln);
    __syncthreads();

    LDSREAD(0, ldsrow) LDSREAD(1, ldsrow) LDSREAD(2, ldsrow) LDSREAD(3, ldsrow)
    LDSREAD(4, ldsrow) LDSREAD(5, ldsrow) LDSREAD(6, ldsrow) LDSREAD(7, ldsrow)

    acc0 = wih0.x * xr.x + wih0.y * xr.y;
    acc1 = wih1.x * xr.x + wih1.y * xr.y;
    acc2 = wih2.x * xr.x + wih2.y * xr.y;
    acc3 = wih3.x * xr.x + wih3.y * xr.y;

    FMA_C(0) FMA_C(1) FMA_C(2) FMA_C(3)
    FMA_C(4) FMA_C(5) FMA_C(6) FMA_C(7)

    REDUCE(0) REDUCE(1) REDUCE(2) REDUCE(3)

    const float iv = sigm(acc0);
    const float fv = sigm(acc1);
    const float gv = tanh_(acc2);
    const float ov = sigm(acc3);
    cst = fv * cst + iv * gv;
    const float hval = ov * tanh_(cst);

    if (ln == 0)
      astoref((((t + 1) & 1) ? hbuf1 : hbuf0) + j, hval);

    __syncthreads();
    if (tid == 0)
      astoreu(slots + b, (u32)(t + 1));
  }

  {
    float* ldsrow = h_lds[0];
    poll_and_stage(slots, hbuf0, TSTEPS, ldsrow, wv, ln);
    __syncthreads();

    float a0 = 0.0f;
    const float* wl = W_lin + (long)j * H;
    #pragma unroll
    for (int k = 0; k < 8; ++k) {
      const vf4 h4 = *(const vf4*)&ldsrow[4 * (ln + 64 * k)];
      const vf4 u  = *(const vf4*)(wl + 4 * (ln + 64 * k));
      a0 += u.x * h4.x + u.y * h4.y + u.z * h4.z + u.w * h4.w;
    }
    a0 += __shfl_xor(a0, 1);  a0 += __shfl_xor(a0, 2);  a0 += __shfl_xor(a0, 4);
    a0 += __shfl_xor(a0, 8);  a0 += __shfl_xor(a0, 16); a0 += __shfl_xor(a0, 32);

    if (ln == 0)
      astoref(hbuf1 + j, a0 + b_lin[j]);
    __syncthreads();
    if (tid == 0)
      astoreu(slots + b, (u32)(TSTEPS + 1));
  }

  if (b == 0 && wv == 0) {
    const u32* sp = slots + 4 * ln;
    int v0 = (int)aload32(sp + 0), v1 = (int)aload32(sp + 1);
    int v2 = (int)aload32(sp + 2), v3 = (int)aload32(sp + 3);
    const int tgt = TSTEPS + 1;
    while (!__all((v0 >= tgt) & (v1 >= tgt) & (v2 >= tgt) & (v3 >= tgt))) {
      __builtin_amdgcn_s_sleep(1);
      if (v0 < tgt) v0 = (int)aload32(sp + 0);
      if (v1 < tgt) v1 = (int)aload32(sp + 1);
      if (v2 < tgt) v2 = (int)aload32(sp + 2);
      if (v3 < tgt) v3 = (int)aload32(sp + 3);
    }
    float p0 = 0.0f, p1 = 0.0f;
    #pragma unroll
    for (int k = 0; k < 16; ++k) {
      const u64 d  = aload64((const u64*)hbuf1 + ln + 64 * k);
      const int c  = 2 * (ln + 64 * k);
      const float ylo = __uint_as_float((u32)d);
      const float yhi = __uint_as_float((u32)(d >> 32));
      p0 = __builtin_fmaf(W_out[c],         ylo, p0);
      p0 = __builtin_fmaf(W_out[c + 1],     yhi, p0);
      p1 = __builtin_fmaf(W_out[H + c],     ylo, p1);
      p1 = __builtin_fmaf(W_out[H + c + 1], yhi, p1);
    }
    p0 += __shfl_xor(p0, 1);  p0 += __shfl_xor(p0, 2);  p0 += __shfl_xor(p0, 4);
    p0 += __shfl_xor(p0, 8);  p0 += __shfl_xor(p0, 16); p0 += __shfl_xor(p0, 32);
    p1 += __shfl_xor(p1, 1);  p1 += __shfl_xor(p1, 2);  p1 += __shfl_xor(p1, 4);
    p1 += __shfl_xor(p1, 8);  p1 += __shfl_xor(p1, 16); p1 += __shfl_xor(p1, 32);
    if (ln == 0) {
      out[0] = p0 + b_out[0];
      out[1] = p1 + b_out[1];
    }
  }
}

extern "C" void kernel_launch(void* const* d_in, const int* in_sizes, int n_in,
                              void* d_out, int out_size, void* d_ws, size_t ws_size,
                              hipStream_t stream) {
  const float* x     = (const float*)d_in[0];
  const float* W_ih  = (const float*)d_in[1];
  const float* W_hh  = (const float*)d_in[2];
  const float* b_ih  = (const float*)d_in[3];
  const float* b_hh  = (const float*)d_in[4];
  const float* W_lin = (const float*)d_in[5];
  const float* b_lin = (const float*)d_in[6];
  const float* W_out = (const float*)d_in[7];
  const float* b_out = (const float*)d_in[8];

  const size_t need = (size_t)2 * NBLK * NBLK * 8 * sizeof(u64);  // 8 MB
  if (ws_size >= need) {
    lstm_mbox<<<dim3(NBLK), dim3(NTHR), 0, stream>>>(
        x, W_ih, W_hh, b_ih, b_hh, W_lin, b_lin, W_out, b_out,
        (float*)d_out, (float*)d_ws);
  } else {
    lstm_persist<<<dim3(NBLK), dim3(NTHR), 0, stream>>>(
        x, W_ih, W_hh, b_ih, b_hh, W_lin, b_lin, W_out, b_out,
        (float*)d_out, (float*)d_ws);
  }
}

// Round 8
// 30027.576 us; speedup vs baseline: 2.3902x; 2.3902x over previous
//
#include <hip/hip_runtime.h>

// Persistent-LSTM MI355X — Round 14: speculative slice read under the gate.
// Session laws: (1) h must be written ONCE and pulled via LLC — push/mailbox
// replication is write-bound death (R13: 134GB HBM writes, 8.4us/step).
// (2) Producer publish MUST be R6's ordering: data stores -> __syncthreads
// drain -> tid0 compact tag (every early/lockfree variant cost +1.5-2us:
// R7/R8/R10/R12). (3) Consumer gate MUST be the compact 2-line tag poll
// (data-region polling storms: R7). (4) Geometry fixed 256x512, weights
// VGPR-resident (R9). (5) Poll pipelining pays ~2-3x its mean-latency value
// through the max-of-256 straggler statistic (R11: -0.27us/step).
// R14 removes the last clean serial L — the POST-detect data read:
//   - h words are self-validating u64 {tag|float} (R12's proven format);
//   - consumer ISSUES its 4 slice-word loads BEFORE the tag poll (read L
//     overlaps detection), validates embedded tags after the gate passes,
//     re-reading only words served before the stores landed (bounded:
//     gate-pass => all words visible => first re-read is fresh);
//   - gate poll deepened to 3 stages (round ~L/3, shaves detect tail).
// R12's retry storm is excluded: the gate fires only after the FULL barrier
// drain, so validation virtually always passes on the in-flight words.
// WAR/freshness (R12's word-tag argument): tag t+2 in parity p requires its
// producer to observe ALL tags >= t+1, which requires every block's step-t
// staging reads complete (stage precedes publish in program order).
// 0xAA ws poison: negative as signed tag -> stale/inert (R3-R12 validated).
// ws: hq u64[2][2048] (32KB) + slots u32[256] (1KB).

#define H      2048
#define TSTEPS 8192
#define FEAT   128
#define NBLK   256
#define NTHR   512

typedef float vf4 __attribute__((ext_vector_type(4)));
typedef float vf2 __attribute__((ext_vector_type(2)));
typedef unsigned long long u64;
typedef unsigned int u32;

__device__ __forceinline__ float sigm(float xv) {
  return __builtin_amdgcn_rcpf(1.0f + __expf(-xv));
}
__device__ __forceinline__ float tanh_(float xv) {
  return 1.0f - 2.0f * __builtin_amdgcn_rcpf(__expf(2.0f * xv) + 1.0f);
}

__device__ __forceinline__ u64 aload64(const u64* p) {
  return __hip_atomic_load(p, __ATOMIC_RELAXED, __HIP_MEMORY_SCOPE_AGENT);
}
__device__ __forceinline__ u32 aload32(const u32* p) {
  return __hip_atomic_load(p, __ATOMIC_RELAXED, __HIP_MEMORY_SCOPE_AGENT);
}
__device__ __forceinline__ void astoreu(u32* p, u32 v) {
  __hip_atomic_store(p, v, __ATOMIC_RELAXED, __HIP_MEMORY_SCOPE_AGENT);
}
__device__ __forceinline__ void astore64(u64* p, u64 v) {
  __hip_atomic_store(p, v, __ATOMIC_RELAXED, __HIP_MEMORY_SCOPE_AGENT);
}
__device__ __forceinline__ int  tag_of(u64 d) { return (int)(u32)(d >> 32); }
__device__ __forceinline__ float val_of(u64 d) { return __uint_as_float((u32)d); }
__device__ __forceinline__ u64  pack(int tag, float v) {
  return ((u64)(u32)tag << 32) | (u64)__float_as_uint(v);
}

#define DECLG(g) vf4 w##g##_0, w##g##_1, w##g##_2, w##g##_3, \
                     w##g##_4, w##g##_5, w##g##_6, w##g##_7; \
                 vf2 wih##g; float bias##g; float acc##g;

#define LOADG(g) { \
  const int row_ = (g) * H + j; \
  const float* wr_ = W_hh + (long)row_ * H; \
  w##g##_0 = *(const vf4*)(wr_ + 4*(ln      )); \
  w##g##_1 = *(const vf4*)(wr_ + 4*(ln +  64)); \
  w##g##_2 = *(const vf4*)(wr_ + 4*(ln + 128)); \
  w##g##_3 = *(const vf4*)(wr_ + 4*(ln + 192)); \
  w##g##_4 = *(const vf4*)(wr_ + 4*(ln + 256)); \
  w##g##_5 = *(const vf4*)(wr_ + 4*(ln + 320)); \
  w##g##_6 = *(const vf4*)(wr_ + 4*(ln + 384)); \
  w##g##_7 = *(const vf4*)(wr_ + 4*(ln + 448)); \
  wih##g  = *(const vf2*)(W_ih + (long)row_ * FEAT + 2*ln); \
  bias##g = b_ih[row_] + b_hh[row_]; }

// Opaque pin: weights become non-rematerializable (cannot re-sink into loop).
#define PIN(g) asm volatile("" : \
  "+v"(w##g##_0), "+v"(w##g##_1), "+v"(w##g##_2), "+v"(w##g##_3), \
  "+v"(w##g##_4), "+v"(w##g##_5), "+v"(w##g##_6), "+v"(w##g##_7), \
  "+v"(wih##g), "+v"(bias##g));

#define LDSREAD(k, ldsrow) \
  const vf4 hv##k = *(const vf4*)&(ldsrow)[4*(ln + 64*(k))];

#define FMA_G(g, c) \
  acc##g = __builtin_fmaf(w##g##_##c.x, h4_.x, acc##g); \
  acc##g = __builtin_fmaf(w##g##_##c.y, h4_.y, acc##g); \
  acc##g = __builtin_fmaf(w##g##_##c.z, h4_.z, acc##g); \
  acc##g = __builtin_fmaf(w##g##_##c.w, h4_.w, acc##g);

#define FMA_C(c) { const vf4 h4_ = hv##c; \
  FMA_G(0, c) FMA_G(1, c) FMA_G(2, c) FMA_G(3, c) }

#define REDUCE(g) { float a_ = acc##g; \
  a_ += __shfl_xor(a_, 1);  a_ += __shfl_xor(a_, 2);  a_ += __shfl_xor(a_, 4); \
  a_ += __shfl_xor(a_, 8);  a_ += __shfl_xor(a_, 16); a_ += __shfl_xor(a_, 32); \
  acc##g = a_ + bias##g; }

// Wave wv: (1) ISSUE the 4 slice-word loads (speculative — overlaps poll);
// (2) 3-deep pipelined compact-tag gate over its 32 producers (2 lines);
// (3) validate the in-flight words' embedded tags; re-read stale words
// (bounded: gate-pass => visible => first re-read fresh); (4) stage to LDS.
__device__ __forceinline__ void poll_and_stage(const u32* __restrict__ slots,
                                               const u64* __restrict__ hq_par,
                                               int tgt,
                                               float* __restrict__ ldsrow,
                                               int wv, int ln) {
  const int base = wv * 256 + 4 * ln;
  const u64* hp = hq_par + base;
  u64 d0 = aload64(hp + 0);          // speculative: in flight during poll
  u64 d1 = aload64(hp + 1);
  u64 d2 = aload64(hp + 2);
  u64 d3 = aload64(hp + 3);

  const u32* sp = slots + wv * 32 + (ln & 31);
  const bool act = (ln < 32);
  int v0 = act ? (int)aload32(sp) : 0x7fffffff;
  int v1 = act ? (int)aload32(sp) : 0x7fffffff;
  int v2 = act ? (int)aload32(sp) : 0x7fffffff;
  while (!__all(v0 >= tgt)) {
    __builtin_amdgcn_s_sleep(1);
    v0 = v1;
    v1 = v2;
    v2 = (act && v1 < tgt) ? (int)aload32(sp) : v1;
  }
  // gate passed: all words visible; validate the speculative data.
  while (!__all((tag_of(d0) >= tgt) & (tag_of(d1) >= tgt) &
                (tag_of(d2) >= tgt) & (tag_of(d3) >= tgt))) {
    if (tag_of(d0) < tgt) d0 = aload64(hp + 0);
    if (tag_of(d1) < tgt) d1 = aload64(hp + 1);
    if (tag_of(d2) < tgt) d2 = aload64(hp + 2);
    if (tag_of(d3) < tgt) d3 = aload64(hp + 3);
  }
  vf4 hv;
  hv.x = val_of(d0);
  hv.y = val_of(d1);
  hv.z = val_of(d2);
  hv.w = val_of(d3);
  *(vf4*)&ldsrow[base] = hv;
}

__global__ __launch_bounds__(NTHR, 2)
void lstm_persist(const float* __restrict__ x,
                  const float* __restrict__ W_ih,
                  const float* __restrict__ W_hh,
                  const float* __restrict__ b_ih,
                  const float* __restrict__ b_hh,
                  const float* __restrict__ W_lin,
                  const float* __restrict__ b_lin,
                  const float* __restrict__ W_out,
                  const float* __restrict__ b_out,
                  float* __restrict__ out,
                  float* __restrict__ ws)
{
  const int tid = threadIdx.x;
  const int b   = blockIdx.x;
  const int wv  = tid >> 6;
  const int ln  = tid & 63;

  // ws: u64 hq[2][H] tagged h words (32KB); parity p serves steps t&1==p;
  // hq[1] reused for ylin (tag TSTEPS+1). slots: u32[256] compact tags.
  u64* hq    = (u64*)ws;
  u32* slots = (u32*)(ws + 4 * H);

  __shared__ __align__(16) float h_lds[2][H];

  // h_0 = 0: zero parity-0 LDS row (512 threads x 16B)
  *(vf4*)&h_lds[0][4 * tid] = (vf4)(0.0f);

  // ---- persistent weights: load then pin ----
  const int j = b * 8 + wv;
  DECLG(0) DECLG(1) DECLG(2) DECLG(3)
  LOADG(0) LOADG(1) LOADG(2) LOADG(3)
  PIN(0) PIN(1) PIN(2) PIN(3)

  __syncthreads();

  float cst = 0.0f;

  #pragma unroll 1
  for (int t = 0; t < TSTEPS; ++t) {
    const vf2 xr = *(const vf2*)(x + (long)t * FEAT + 2 * ln);
    float* ldsrow = h_lds[t & 1];

    if (t > 0)
      poll_and_stage(slots, hq + (t & 1) * H, t, ldsrow, wv, ln);
    __syncthreads();   // barrier #1: all slices staged before any LDS read

    LDSREAD(0, ldsrow) LDSREAD(1, ldsrow) LDSREAD(2, ldsrow) LDSREAD(3, ldsrow)
    LDSREAD(4, ldsrow) LDSREAD(5, ldsrow) LDSREAD(6, ldsrow) LDSREAD(7, ldsrow)

    acc0 = wih0.x * xr.x + wih0.y * xr.y;
    acc1 = wih1.x * xr.x + wih1.y * xr.y;
    acc2 = wih2.x * xr.x + wih2.y * xr.y;
    acc3 = wih3.x * xr.x + wih3.y * xr.y;

    FMA_C(0) FMA_C(1) FMA_C(2) FMA_C(3)
    FMA_C(4) FMA_C(5) FMA_C(6) FMA_C(7)

    REDUCE(0) REDUCE(1) REDUCE(2) REDUCE(3)

    // gate order [i, f, g, o]
    const float iv = sigm(acc0);
    const float fv = sigm(acc1);
    const float gv = tanh_(acc2);
    const float ov = sigm(acc3);
    cst = fv * cst + iv * gv;
    const float hval = ov * tanh_(cst);

    // publish h_{t+1} (R6-validated ordering, u64 self-validating word):
    // word store -> __syncthreads (drains vmcnt per wave) -> tid0 tag.
    if (ln == 0)
      astore64(hq + ((t + 1) & 1) * H + j, pack(t + 1, hval));
    __syncthreads();   // barrier #2: all 8 words visible before tag below
    if (tid == 0)
      astoreu(slots + b, (u32)(t + 1));
  }

  // ---- head phase 1: ylin[j] = b_lin[j] + dot(W_lin[j,:], h_final) ----
  // h_final words: parity 0, tag TSTEPS. After all waves pass their gate
  // subsets + barrier, all 256 blocks finished step-8191 parity-1 reads ->
  // ylin store into hq[1] is WAR-safe.
  {
    float* ldsrow = h_lds[0];
    poll_and_stage(slots, hq, TSTEPS, ldsrow, wv, ln);
    __syncthreads();

    float a0 = 0.0f;
    const float* wl = W_lin + (long)j * H;
    #pragma unroll
    for (int k = 0; k < 8; ++k) {
      const vf4 h4 = *(const vf4*)&ldsrow[4 * (ln + 64 * k)];
      const vf4 u  = *(const vf4*)(wl + 4 * (ln + 64 * k));
      a0 += u.x * h4.x + u.y * h4.y + u.z * h4.z + u.w * h4.w;
    }
    a0 += __shfl_xor(a0, 1);  a0 += __shfl_xor(a0, 2);  a0 += __shfl_xor(a0, 4);
    a0 += __shfl_xor(a0, 8);  a0 += __shfl_xor(a0, 16); a0 += __shfl_xor(a0, 32);

    if (ln == 0)
      astore64(hq + H + j, pack(TSTEPS + 1, a0 + b_lin[j]));  // ylin word
    __syncthreads();   // drains vmcnt -> ylin visible before tag below
    if (tid == 0)
      astoreu(slots + b, (u32)(TSTEPS + 1));
  }

  // ---- head phase 2: y = ylin @ W_out.T + b_out (block 0, wave 0) ----
  // Barrier-ordered slot protocol; reads issued after gate (fresh).
  if (b == 0 && wv == 0) {
    const u32* sp = slots + 4 * ln;
    int v0 = (int)aload32(sp + 0), v1 = (int)aload32(sp + 1);
    int v2 = (int)aload32(sp + 2), v3 = (int)aload32(sp + 3);
    const int tgt = TSTEPS + 1;
    while (!__all((v0 >= tgt) & (v1 >= tgt) & (v2 >= tgt) & (v3 >= tgt))) {
      __builtin_amdgcn_s_sleep(1);
      if (v0 < tgt) v0 = (int)aload32(sp + 0);
      if (v1 < tgt) v1 = (int)aload32(sp + 1);
      if (v2 < tgt) v2 = (int)aload32(sp + 2);
      if (v3 < tgt) v3 = (int)aload32(sp + 3);
    }
    float p0 = 0.0f, p1 = 0.0f;
    #pragma unroll
    for (int k = 0; k < 32; ++k) {
      const u64 d  = aload64(hq + H + ln + 64 * k);
      const float y = val_of(d);
      const int c  = ln + 64 * k;
      p0 = __builtin_fmaf(W_out[c],     y, p0);
      p1 = __builtin_fmaf(W_out[H + c], y, p1);
    }
    p0 += __shfl_xor(p0, 1);  p0 += __shfl_xor(p0, 2);  p0 += __shfl_xor(p0, 4);
    p0 += __shfl_xor(p0, 8);  p0 += __shfl_xor(p0, 16); p0 += __shfl_xor(p0, 32);
    p1 += __shfl_xor(p1, 1);  p1 += __shfl_xor(p1, 2);  p1 += __shfl_xor(p1, 4);
    p1 += __shfl_xor(p1, 8);  p1 += __shfl_xor(p1, 16); p1 += __shfl_xor(p1, 32);
    if (ln == 0) {
      out[0] = p0 + b_out[0];
      out[1] = p1 + b_out[1];
    }
  }
}

extern "C" void kernel_launch(void* const* d_in, const int* in_sizes, int n_in,
                              void* d_out, int out_size, void* d_ws, size_t ws_size,
                              hipStream_t stream) {
  const float* x     = (const float*)d_in[0];
  const float* W_ih  = (const float*)d_in[1];
  const float* W_hh  = (const float*)d_in[2];
  const float* b_ih  = (const float*)d_in[3];
  const float* b_hh  = (const float*)d_in[4];
  const float* W_lin = (const float*)d_in[5];
  const float* b_lin = (const float*)d_in[6];
  const float* W_out = (const float*)d_in[7];
  const float* b_out = (const float*)d_in[8];

  lstm_persist<<<dim3(NBLK), dim3(NTHR), 0, stream>>>(
      x, W_ih, W_hh, b_ih, b_hh, W_lin, b_lin, W_out, b_out,
      (float*)d_out, (float*)d_ws);
}